// Round 1
// baseline (812.402 us; speedup 1.0000x reference)
//
#include <hip/hip_runtime.h>
#include <math.h>

typedef __attribute__((ext_vector_type(8))) short bf16x8;   // 8 bf16 in 4 VGPRs
typedef __attribute__((ext_vector_type(4))) float f32x4;

#define BSZ 8
#define SEQ 2048
#define DIM 512
#define BS_TOT (BSZ*SEQ)       // 16384
#define BM 32                  // queries per block (attention)
#define BN 64                  // keys per j-tile

__device__ __forceinline__ unsigned short f2bf(float f) {
    unsigned int u = __float_as_uint(f);
    unsigned int r = (u + 0x7fffu + ((u >> 16) & 1u)) >> 16;
    return (unsigned short)r;
}

// ---------------- fp32 -> bf16 conversion (vector4) ----------------
__global__ __launch_bounds__(256) void conv_f2b(const float* __restrict__ src,
                                                unsigned short* __restrict__ dst, int n4) {
    int i = blockIdx.x * blockDim.x + threadIdx.x;
    if (i < n4) {
        float4 v = ((const float4*)src)[i];
        ushort4 o;
        o.x = f2bf(v.x); o.y = f2bf(v.y); o.z = f2bf(v.z); o.w = f2bf(v.w);
        ((ushort4*)dst)[i] = o;
    }
}

// ---------------- per-point trig table (SoA, 5 planes) ----------------
__global__ __launch_bounds__(256) void trig_prep(const float* __restrict__ lat,
                                                 const float* __restrict__ lon,
                                                 float* __restrict__ trig) {
    int i = blockIdx.x * blockDim.x + threadIdx.x;
    if (i < BS_TOT) {
        const float RAD = 0.017453292519943295f;
        float la = lat[i] * RAD, lo = lon[i] * RAD;
        trig[0 * BS_TOT + i] = sinf(la * 0.5f);
        trig[1 * BS_TOT + i] = cosf(la * 0.5f);
        trig[2 * BS_TOT + i] = sinf(lo * 0.5f);
        trig[3 * BS_TOT + i] = cosf(lo * 0.5f);
        trig[4 * BS_TOT + i] = cosf(la);
    }
}

// ---------------- QKV projection GEMM (bf16 MFMA) ----------------
// out[s][e] = sum_d x[s][d] * W[e][d] + b[e]
// blockIdx.z: 0=Q, 1=K (row-major [16384][512]), 2=V (transposed per batch [512][2048])
__global__ __launch_bounds__(256) void qkv_gemm(
    const unsigned short* __restrict__ xb,
    const unsigned short* __restrict__ Wqb, const unsigned short* __restrict__ Wkb,
    const unsigned short* __restrict__ Wvb,
    const float* __restrict__ bq, const float* __restrict__ bk, const float* __restrict__ bv,
    unsigned short* __restrict__ Qb, unsigned short* __restrict__ Kb,
    unsigned short* __restrict__ VTb) {
    const int which = blockIdx.z;
    const unsigned short* W = (which == 0) ? Wqb : (which == 1) ? Wkb : Wvb;
    const float* bias = (which == 0) ? bq : (which == 1) ? bk : bv;

    const int tid = threadIdx.x;
    const int lane = tid & 63, w = tid >> 6;
    const int lq = lane & 15, quad = lane >> 4;
    const int m0 = blockIdx.x * 64, n0 = blockIdx.y * 64;

    const unsigned short* abase = xb + (size_t)(m0 + w * 16 + lq) * DIM + quad * 8;
    const unsigned short* bbase = W + (size_t)(n0 + lq) * DIM + quad * 8;

    f32x4 acc[4];
    #pragma unroll
    for (int c = 0; c < 4; ++c) acc[c] = (f32x4){0.f, 0.f, 0.f, 0.f};

    #pragma unroll
    for (int ks = 0; ks < 16; ++ks) {
        bf16x8 a = *(const bf16x8*)(abase + ks * 32);
        #pragma unroll
        for (int c = 0; c < 4; ++c) {
            bf16x8 bfrag = *(const bf16x8*)(bbase + (size_t)c * 16 * DIM + ks * 32);
            acc[c] = __builtin_amdgcn_mfma_f32_16x16x32_bf16(a, bfrag, acc[c], 0, 0, 0);
        }
    }

    #pragma unroll
    for (int c = 0; c < 4; ++c) {
        int e = n0 + c * 16 + lq;
        float be = bias[e];
        #pragma unroll
        for (int r = 0; r < 4; ++r) {
            int rg = m0 + w * 16 + quad * 4 + r;   // global flat row (b*S+s)
            float v = acc[c][r] + be;
            if (which == 0) {
                Qb[(size_t)rg * DIM + e] = f2bf(v);
            } else if (which == 1) {
                Kb[(size_t)rg * DIM + e] = f2bf(v);
            } else {
                int bb = rg >> 11, s = rg & 2047;
                VTb[((size_t)bb * DIM + e) * SEQ + s] = f2bf(v);
            }
        }
    }
}

// ---------------- fused flash attention with spatio-temporal bias ----------------
__global__ __launch_bounds__(512) void attn_kernel(
    const unsigned short* __restrict__ Qb,
    const unsigned short* __restrict__ Kb,
    const unsigned short* __restrict__ VTb,
    const float* __restrict__ trig,
    const float* __restrict__ time_seq,
    const int* __restrict__ mask,
    float* __restrict__ Out) {
    __shared__ unsigned short Qs[BM][520];   // Q tile, bf16, padded stride
    __shared__ float Sl[BM][68];             // scores fp32
    __shared__ unsigned short Pld[BM][72];   // probs bf16 (A-operand readable)
    __shared__ float ktrig[5][BN];
    __shared__ float ktime[BN];
    __shared__ int   kmask[BN];
    __shared__ float qtrig[5][BM];
    __shared__ float qtime[BM];
    __shared__ float mrow[BM], lrow[BM], arow[BM];

    const int tid = threadIdx.x;
    const int wave = tid >> 6, lane = tid & 63;
    const int lq = lane & 15, quad = lane >> 4;
    const int h = wave >> 2, wv = wave & 3;   // h: query half, wv: col group
    const int b = blockIdx.y;
    const int i0 = blockIdx.x * BM;

    // stage Q tile (BM x 512 bf16)
    {
        const unsigned short* qsrc = Qb + (size_t)(b * SEQ + i0) * DIM;
        for (int idx = tid; idx < BM * 64; idx += 512) {
            int r = idx >> 6, c = idx & 63;
            *(uint4*)&Qs[r][c * 8] = *(const uint4*)(qsrc + (size_t)r * DIM + c * 8);
        }
    }
    if (tid < BM) {
        int g = b * SEQ + i0 + tid;
        #pragma unroll
        for (int j = 0; j < 5; ++j) qtrig[j][tid] = trig[j * BS_TOT + g];
        qtime[tid] = time_seq[g];
        mrow[tid] = -__builtin_inff();
        lrow[tid] = 0.f;
    }

    f32x4 acc[8];
    #pragma unroll
    for (int n = 0; n < 8; ++n) acc[n] = (f32x4){0.f, 0.f, 0.f, 0.f};

    const float scale = 0.04419417382415922f;   // 1/sqrt(512)

    for (int jt = 0; jt < SEQ / BN; ++jt) {
        const int j0 = jt * BN;
        __syncthreads();   // (A) prev PV done; Q/init visible on first iter
        if (tid < BN) {
            int g = b * SEQ + j0 + tid;
            #pragma unroll
            for (int j = 0; j < 5; ++j) ktrig[j][tid] = trig[j * BS_TOT + g];
            ktime[tid] = time_seq[g];
            kmask[tid] = mask[g];
        }
        // ---- QK^T: 16x16 tile per wave, K = 512 ----
        f32x4 sfrag = (f32x4){0.f, 0.f, 0.f, 0.f};
        {
            const unsigned short* kb =
                Kb + (size_t)(b * SEQ + j0 + wv * 16 + lq) * DIM + quad * 8;
            const unsigned short* qb = &Qs[h * 16 + lq][quad * 8];
            #pragma unroll
            for (int ks = 0; ks < 16; ++ks) {
                bf16x8 af = *(const bf16x8*)(qb + ks * 32);
                bf16x8 bfr = *(const bf16x8*)(kb + ks * 32);
                sfrag = __builtin_amdgcn_mfma_f32_16x16x32_bf16(af, bfr, sfrag, 0, 0, 0);
            }
        }
        __syncthreads();   // (B) k staging visible
        // ---- bias + mask, write scores ----
        {
            int kk = wv * 16 + lq;
            float k_sl = ktrig[0][kk], k_cl = ktrig[1][kk];
            float k_slo = ktrig[2][kk], k_clo = ktrig[3][kk], k_cla = ktrig[4][kk];
            float kt = ktime[kk];
            int km = kmask[kk];
            #pragma unroll
            for (int r = 0; r < 4; ++r) {
                int q = h * 16 + quad * 4 + r;
                float sdlat = k_sl * qtrig[1][q] - k_cl * qtrig[0][q];
                float sdlon = k_slo * qtrig[3][q] - k_clo * qtrig[2][q];
                float a = sdlat * sdlat + qtrig[4][q] * k_cla * (sdlon * sdlon);
                a = fminf(fmaxf(a, 0.0f), 1.0f);
                float ds = 12742.0f * asinf(sqrtf(a));
                float dt = fabsf(kt - qtime[q]);
                float sval = sfrag[r] * scale - ds - dt;
                if (km == 0) sval = -1e9f;
                Sl[q][kk] = sval;
            }
        }
        __syncthreads();   // (C) scores visible
        // ---- online softmax over this tile (16 threads per row) ----
        {
            int r = tid >> 4, c = tid & 15;
            float s0 = Sl[r][c], s1 = Sl[r][c + 16], s2 = Sl[r][c + 32], s3 = Sl[r][c + 48];
            float mx = fmaxf(fmaxf(s0, s1), fmaxf(s2, s3));
            #pragma unroll
            for (int o = 1; o < 16; o <<= 1) mx = fmaxf(mx, __shfl_xor(mx, o, 16));
            float m_old = mrow[r];
            float m_new = fmaxf(m_old, mx);
            float p0 = __expf(s0 - m_new), p1 = __expf(s1 - m_new);
            float p2 = __expf(s2 - m_new), p3 = __expf(s3 - m_new);
            float sm = p0 + p1 + p2 + p3;
            #pragma unroll
            for (int o = 1; o < 16; o <<= 1) sm += __shfl_xor(sm, o, 16);
            Pld[r][c] = f2bf(p0);
            Pld[r][c + 16] = f2bf(p1);
            Pld[r][c + 32] = f2bf(p2);
            Pld[r][c + 48] = f2bf(p3);
            if (c == 0) {
                float alpha = __expf(m_old - m_new);
                arow[r] = alpha;
                mrow[r] = m_new;
                lrow[r] = lrow[r] * alpha + sm;
            }
        }
        __syncthreads();   // (D) P/alpha visible
        // ---- rescale O, then PV ----
        {
            float al[4];
            #pragma unroll
            for (int r = 0; r < 4; ++r) al[r] = arow[h * 16 + quad * 4 + r];
            #pragma unroll
            for (int n = 0; n < 8; ++n)
                #pragma unroll
                for (int r = 0; r < 4; ++r) acc[n][r] *= al[r];

            bf16x8 p0f = *(const bf16x8*)&Pld[h * 16 + lq][quad * 8];
            bf16x8 p1f = *(const bf16x8*)&Pld[h * 16 + lq][32 + quad * 8];
            const unsigned short* vb =
                VTb + (size_t)(b * DIM + wv * 128 + lq) * SEQ + j0 + quad * 8;
            #pragma unroll
            for (int n = 0; n < 8; ++n) {
                bf16x8 v0 = *(const bf16x8*)(vb + (size_t)n * 16 * SEQ);
                bf16x8 v1 = *(const bf16x8*)(vb + (size_t)n * 16 * SEQ + 32);
                acc[n] = __builtin_amdgcn_mfma_f32_16x16x32_bf16(p0f, v0, acc[n], 0, 0, 0);
                acc[n] = __builtin_amdgcn_mfma_f32_16x16x32_bf16(p1f, v1, acc[n], 0, 0, 0);
            }
        }
    }

    // epilogue: normalize and write
    {
        float inv[4];
        #pragma unroll
        for (int r = 0; r < 4; ++r) inv[r] = 1.0f / lrow[h * 16 + quad * 4 + r];
        #pragma unroll
        for (int n = 0; n < 8; ++n) {
            #pragma unroll
            for (int r = 0; r < 4; ++r) {
                int q = h * 16 + quad * 4 + r;
                Out[(size_t)(b * SEQ + i0 + q) * DIM + wv * 128 + n * 16 + lq] =
                    acc[n][r] * inv[r];
            }
        }
    }
}

extern "C" void kernel_launch(void* const* d_in, const int* in_sizes, int n_in,
                              void* d_out, int out_size, void* d_ws, size_t ws_size,
                              hipStream_t stream) {
    const float* x    = (const float*)d_in[0];
    const float* tseq = (const float*)d_in[1];
    const float* lat  = (const float*)d_in[2];
    const float* lon  = (const float*)d_in[3];
    const int*   mk   = (const int*)d_in[4];
    const float* Wq   = (const float*)d_in[5];
    const float* bq   = (const float*)d_in[6];
    const float* Wk   = (const float*)d_in[7];
    const float* bk   = (const float*)d_in[8];
    const float* Wv   = (const float*)d_in[9];
    const float* bv   = (const float*)d_in[10];
    float* out = (float*)d_out;

    unsigned short* xb  = (unsigned short*)d_ws;                  // 16 MB
    unsigned short* Qb  = xb + (size_t)BS_TOT * DIM;
    unsigned short* Kb  = Qb + (size_t)BS_TOT * DIM;
    unsigned short* VTb = Kb + (size_t)BS_TOT * DIM;
    unsigned short* Wqb = VTb + (size_t)BS_TOT * DIM;
    unsigned short* Wkb = Wqb + DIM * DIM;
    unsigned short* Wvb = Wkb + DIM * DIM;
    float* trig = (float*)(Wvb + DIM * DIM);                      // 5 planes x 16384

    conv_f2b<<<(BS_TOT * DIM / 4 + 255) / 256, 256, 0, stream>>>(x, xb, BS_TOT * DIM / 4);
    conv_f2b<<<(DIM * DIM / 4 + 255) / 256, 256, 0, stream>>>(Wq, Wqb, DIM * DIM / 4);
    conv_f2b<<<(DIM * DIM / 4 + 255) / 256, 256, 0, stream>>>(Wk, Wkb, DIM * DIM / 4);
    conv_f2b<<<(DIM * DIM / 4 + 255) / 256, 256, 0, stream>>>(Wv, Wvb, DIM * DIM / 4);
    trig_prep<<<(BS_TOT + 255) / 256, 256, 0, stream>>>(lat, lon, trig);

    qkv_gemm<<<dim3(BS_TOT / 64, DIM / 64, 3), 256, 0, stream>>>(
        xb, Wqb, Wkb, Wvb, bq, bk, bv, Qb, Kb, VTb);

    attn_kernel<<<dim3(SEQ / BM, BSZ), 512, 0, stream>>>(
        Qb, Kb, VTb, trig, tseq, mk, out);
}